// Round 4
// baseline (350.319 us; speedup 1.0000x reference)
//
#include <hip/hip_runtime.h>
#include <hip/hip_bf16.h>
#include <cstdint>
#include <cstddef>

// Problem: B=4, T=4096, D=1024, H=16, HD=64.
// qkv = x @ Wqkv  (16384x1024 @ 1024x3072)
// per-token head-attention: scores[i,j] = q_i . k_j / 8 over heads i,j (16x16), softmax_j, out = P @ v
// final = out @ Wout (16384x1024 @ 1024x1024)
//
// Layout trick: qkv and ao are stored PERMUTED per token so the attention
// kernel's loads/stores are fully coalesced. The permutations are absorbed
// into the weight-transpose kernels (wqkvT row order, woutT k order), so both
// GEMMs are untouched and contraction stays positionally consistent.

typedef __bf16 bf16x8 __attribute__((ext_vector_type(8)));
typedef __bf16 bf16x4 __attribute__((ext_vector_type(4)));
typedef float  f32x4  __attribute__((ext_vector_type(4)));

#define AS1 __attribute__((address_space(1)))
#define AS3 __attribute__((address_space(3)))

__device__ __forceinline__ void async_copy16(const void* g, void* l) {
    __builtin_amdgcn_global_load_lds((const AS1 void*)g, (AS3 void*)l, 16, 0, 0);
}

// position p in the permuted qkv token-row holds original column pi(p).
// inverse map: original col -> position.
// q/k (g<2): col=g*1024+h*64+d -> p = g*1024 + (d&32)*16 + ((d>>3)&3)*128 + h*8 + (d&7)
//   (so attn lane reads A-frag at base + lane*8 (+512 for d>=32))
// v (g==2): col=2048+j*64+d -> p = 2048 + d*16 + j   (V transposed: B-frag direct load)
__device__ __forceinline__ int invp_qkv(int col) {
    int g = col >> 10;
    if (g == 2) { int q = col & 1023; return 2048 + ((q & 63) << 4) + (q >> 6); }
    int h = (col >> 6) & 15, d = col & 63;
    return (g << 10) + ((d & 32) << 4) + (((d >> 3) & 3) << 7) + (h << 3) + (d & 7);
}

// ao position map: original k = i*64+d -> p = (i>>2)*256 + (d&15)*16 + (d>>4)*4 + (i&3)
// (attn lane stores its 16 C-layout values contiguously at lane*16)
__device__ __forceinline__ int invp_ao(int k) {
    return (((k >> 8) & 3) << 8) + ((k & 15) << 4) + (((k >> 4) & 3) << 2) + ((k >> 6) & 3);
}

// ---------------- convert fp32 -> bf16 (vectorized) ----------------
__global__ __launch_bounds__(256) void cvt_bf16_kernel(const float4* __restrict__ in,
                                                       bf16x4* __restrict__ out, int n4) {
    int i = blockIdx.x * 256 + threadIdx.x;
    if (i >= n4) return;
    float4 v = in[i];
    bf16x4 o = { (__bf16)v.x, (__bf16)v.y, (__bf16)v.z, (__bf16)v.w };
    out[i] = o;
}

// ---------------- transpose + convert Wqkv: out row order permuted ----------------
// out[invp_qkv(n)][k] = (bf16)Wqkv[k][n].  R=1024 (k), C=3072 (n).
__global__ __launch_bounds__(256) void transpose_qkv_kernel(const float* __restrict__ in,
                                                            __bf16* __restrict__ out) {
    __shared__ float tile[32][33];
    const int C = 3072;
    int c0 = blockIdx.x * 32, r0 = blockIdx.y * 32;
    int tx = threadIdx.x, ty = threadIdx.y; // 32 x 8
    #pragma unroll
    for (int i = 0; i < 32; i += 8)
        tile[ty + i][tx] = in[(size_t)(r0 + ty + i) * C + c0 + tx];
    __syncthreads();
    #pragma unroll
    for (int i = 0; i < 32; i += 8) {
        int prow = invp_qkv(c0 + ty + i);
        out[(size_t)prow * 1024 + r0 + tx] = (__bf16)tile[tx][ty + i];
    }
}

// ---------------- transpose + convert Wout: k (inner) order permuted ----------------
// out[n][invp_ao(k)] = (bf16)Wout[k][n].  1024 x 1024.
__global__ __launch_bounds__(256) void transpose_wout_kernel(const float* __restrict__ in,
                                                             __bf16* __restrict__ out) {
    __shared__ float tile[32][33];
    const int C = 1024;
    int c0 = blockIdx.x * 32, r0 = blockIdx.y * 32;
    int tx = threadIdx.x, ty = threadIdx.y; // 32 x 8
    #pragma unroll
    for (int i = 0; i < 32; i += 8)
        tile[ty + i][tx] = in[(size_t)(r0 + ty + i) * C + c0 + tx];
    __syncthreads();
    int pk = invp_ao(r0 + tx);
    #pragma unroll
    for (int i = 0; i < 32; i += 8)
        out[(size_t)(c0 + ty + i) * 1024 + pk] = (__bf16)tile[tx][ty + i];
}

// ---------------- bf16 GEMM, C = A @ Bt^T ----------------
// A: M x K bf16 row-major, Bt: N x K bf16 row-major (i.e. B transposed)
// 128x128 block tile, BK=32, 4 waves in 2x2, each wave 64x64 via 4x4 mfma_16x16x32.
template<int OUT_BF16>
__global__ __launch_bounds__(256) void gemm_bt(const __bf16* __restrict__ A,
                                               const __bf16* __restrict__ Bt,
                                               void* __restrict__ Cv,
                                               int N, int K) {
    __shared__ __bf16 As[128 * 32]; // [row][k] 64B rows, k-slots xor-swizzled
    __shared__ __bf16 Bs[128 * 32];

    const int tid  = threadIdx.x;
    const int wave = tid >> 6;
    const int lane = tid & 63;
    const int quad = lane >> 4;
    const int q16  = lane & 15;
    const int wr   = wave >> 1, wc = wave & 1;
    const int row0 = blockIdx.y * 128;
    const int col0 = blockIdx.x * 128;

    const __bf16* Ag = A  + (size_t)row0 * K;
    const __bf16* Bg = Bt + (size_t)col0 * K;

    // per-wave staging: 2 chunks of 1KB each for A and B tiles (8KB each)
    const int o0 = (wave * 2)     * 1024 + lane * 16; // byte offset in tile
    const int o1 = (wave * 2 + 1) * 1024 + lane * 16;
    const int r0 = o0 >> 6, r1 = o1 >> 6;             // tile row (64B rows)
    const int cb0 = ((o0 >> 4) & 3) ^ ((r0 >> 1) & 3); // logical k-group (swizzle)
    const int cb1 = ((o1 >> 4) & 3) ^ ((r1 >> 1) & 3);
    char* ldsA0 = (char*)As + (wave * 2)     * 1024;
    char* ldsA1 = (char*)As + (wave * 2 + 1) * 1024;
    char* ldsB0 = (char*)Bs + (wave * 2)     * 1024;
    char* ldsB1 = (char*)Bs + (wave * 2 + 1) * 1024;

    f32x4 acc[4][4] = {};

    for (int k0 = 0; k0 < K; k0 += 32) {
        async_copy16(Ag + (size_t)r0 * K + (k0 + cb0 * 8), ldsA0);
        async_copy16(Ag + (size_t)r1 * K + (k0 + cb1 * 8), ldsA1);
        async_copy16(Bg + (size_t)r0 * K + (k0 + cb0 * 8), ldsB0);
        async_copy16(Bg + (size_t)r1 * K + (k0 + cb1 * 8), ldsB1);
        __syncthreads(); // drains vmcnt(0): staged data visible

        bf16x8 af[4], bfr[4];
        #pragma unroll
        for (int mi = 0; mi < 4; ++mi) {
            int row = wr * 64 + mi * 16 + q16;
            int sl  = quad ^ ((row >> 1) & 3);
            af[mi] = *(const bf16x8*)((const char*)As + row * 64 + sl * 16);
        }
        #pragma unroll
        for (int ni = 0; ni < 4; ++ni) {
            int row = wc * 64 + ni * 16 + q16;
            int sl  = quad ^ ((row >> 1) & 3);
            bfr[ni] = *(const bf16x8*)((const char*)Bs + row * 64 + sl * 16);
        }
        #pragma unroll
        for (int mi = 0; mi < 4; ++mi)
            #pragma unroll
            for (int ni = 0; ni < 4; ++ni)
                acc[mi][ni] = __builtin_amdgcn_mfma_f32_16x16x32_bf16(af[mi], bfr[ni], acc[mi][ni], 0, 0, 0);
        __syncthreads(); // all reads done before next stage overwrites
    }

    // epilogue: D row = quad*4 + reg, col = q16 (per 16x16 tile)
    #pragma unroll
    for (int mi = 0; mi < 4; ++mi) {
        #pragma unroll
        for (int ni = 0; ni < 4; ++ni) {
            int col = col0 + wc * 64 + ni * 16 + q16;
            #pragma unroll
            for (int r = 0; r < 4; ++r) {
                int row = row0 + wr * 64 + mi * 16 + quad * 4 + r;
                if (OUT_BF16)
                    ((__bf16*)Cv)[(size_t)row * N + col] = (__bf16)acc[mi][ni][r];
                else
                    ((float*)Cv)[(size_t)row * N + col] = acc[mi][ni][r];
            }
        }
    }
}

// ---------------- per-token head attention, MFMA, one wave per token ----------------
// qkv token-row is in permuted layout (see invp_qkv): all loads coalesced,
// V pre-transposed -> direct B-frag loads. No LDS, no barriers.
// S^T = K.Q^T via mfma_16x16x32 (C-layout: j=quad*4+r, i=q16); softmax over j;
// P^T C-layout -> A-frag of P (K padded to 32) via cross-quad dword shuffle.
// Output stored per invp_ao: 2 coalesced b128 stores per lane.
__global__ __launch_bounds__(256) void attn_mfma_kernel(const __bf16* __restrict__ qkv,
                                                        __bf16* __restrict__ ao) {
    const int tok  = blockIdx.x * 4 + (threadIdx.x >> 6);
    const int lane = threadIdx.x & 63;
    const int quad = lane >> 4;
    const int q16  = lane & 15;

    const __bf16* base = qkv + (size_t)tok * 3072;

    // coalesced A-frag loads (layout puts lane's fragment at lane*8)
    const bf16x8 qf0 = *(const bf16x8*)(base + lane * 8);
    const bf16x8 qf1 = *(const bf16x8*)(base + 512 + lane * 8);
    const bf16x8 kf0 = *(const bf16x8*)(base + 1024 + lane * 8);
    const bf16x8 kf1 = *(const bf16x8*)(base + 1536 + lane * 8);

    // S^T[j][i] = sum_d k[j][d] q[i][d]
    f32x4 st = {0.f, 0.f, 0.f, 0.f};
    st = __builtin_amdgcn_mfma_f32_16x16x32_bf16(kf0, qf0, st, 0, 0, 0);
    st = __builtin_amdgcn_mfma_f32_16x16x32_bf16(kf1, qf1, st, 0, 0, 0);

    // softmax over j (= 4 regs x 4 quads) for fixed i = q16
    float s0 = st[0] * 0.125f, s1 = st[1] * 0.125f, s2 = st[2] * 0.125f, s3 = st[3] * 0.125f;
    float m = fmaxf(fmaxf(s0, s1), fmaxf(s2, s3));
    m = fmaxf(m, __shfl_xor(m, 16));
    m = fmaxf(m, __shfl_xor(m, 32));
    float e0 = __expf(s0 - m), e1 = __expf(s1 - m), e2 = __expf(s2 - m), e3 = __expf(s3 - m);
    float sum = e0 + e1 + e2 + e3;
    sum += __shfl_xor(sum, 16);
    sum += __shfl_xor(sum, 32);
    const float inv = 1.f / sum;

    // pack P^T lane values (j = quad*4 + r, i = q16) into 2 dwords of bf16
    union { __bf16 h[2]; int i; } u01, u23;
    u01.h[0] = (__bf16)(e0 * inv); u01.h[1] = (__bf16)(e1 * inv);
    u23.h[0] = (__bf16)(e2 * inv); u23.h[1] = (__bf16)(e3 * inv);

    // A-frag of P for 16x16x32 (K padded to 32): lane needs P[q16][quad*8+idx]
    // = P^T[quad*8+idx][q16]; source lanes quad*32+q16 (idx 0..3) and +16 (idx 4..7).
    const int src0 = quad * 32 + q16;
    const int src1 = src0 + 16;
    union { int i[4]; bf16x8 v; } af;
    af.i[0] = __shfl(u01.i, src0);
    af.i[1] = __shfl(u23.i, src0);
    af.i[2] = __shfl(u01.i, src1);
    af.i[3] = __shfl(u23.i, src1);
    if (quad >= 2) { af.i[0] = 0; af.i[1] = 0; af.i[2] = 0; af.i[3] = 0; }

    // PV: V region is pre-transposed [d][j]; B-frag chunk c is a direct load:
    // lane (quad<2) reads v[j=quad*8..+7][d=c*16+q16] contiguously.
    const __bf16* vb = base + 2048;
    f32x4 accs[4];
    #pragma unroll
    for (int c = 0; c < 4; ++c) {
        bf16x8 bfv = {};
        if (quad < 2)
            bfv = *(const bf16x8*)(vb + (c * 16 + q16) * 16 + quad * 8);
        f32x4 z = {0.f, 0.f, 0.f, 0.f};
        accs[c] = __builtin_amdgcn_mfma_f32_16x16x32_bf16(af.v, bfv, z, 0, 0, 0);
    }

    // store: lane's 16 values (out[i=quad*4+r][d=c*16+q16]) at p = lane*16 + c*4 + r
    union { __bf16 h[16]; bf16x8 v[2]; } o;
    #pragma unroll
    for (int c = 0; c < 4; ++c)
        #pragma unroll
        for (int r = 0; r < 4; ++r)
            o.h[c * 4 + r] = (__bf16)accs[c][r];
    __bf16* outp = ao + (size_t)tok * 1024 + lane * 16;
    *(bf16x8*)outp = o.v[0];
    *(bf16x8*)(outp + 8) = o.v[1];
}

// ---------------- launch ----------------
extern "C" void kernel_launch(void* const* d_in, const int* in_sizes, int n_in,
                              void* d_out, int out_size, void* d_ws, size_t ws_size,
                              hipStream_t stream) {
    const float* x    = (const float*)d_in[0]; // 16384 x 1024
    const float* Wqkv = (const float*)d_in[1]; // 1024 x 3072
    const float* Wout = (const float*)d_in[2]; // 1024 x 1024
    float* out = (float*)d_out;                // 16384 x 1024

    char* ws = (char*)d_ws;
    __bf16* xb    = (__bf16*)(ws);                                   // 32 MiB
    __bf16* wqkvT = (__bf16*)(ws + 33554432);                        // 6 MiB  (3072 x 1024, row-permuted)
    __bf16* woutT = (__bf16*)(ws + 33554432 + 6291456);              // 2 MiB  (1024 x 1024, k-permuted)
    __bf16* qkv   = (__bf16*)(ws + 33554432 + 6291456 + 2097152);    // 96 MiB (16384 x 3072, permuted)
    __bf16* ao    = (__bf16*)(ws + 33554432 + 6291456 + 2097152 + 100663296); // 32 MiB (permuted)

    // convert x (16M elems, 4/thread)
    cvt_bf16_kernel<<<16384, 256, 0, stream>>>((const float4*)x, (bf16x4*)xb, 4194304);
    // transpose+convert weights (with absorbed layout permutations)
    transpose_qkv_kernel<<<dim3(96, 32), dim3(32, 8), 0, stream>>>(Wqkv, wqkvT);
    transpose_wout_kernel<<<dim3(32, 32), dim3(32, 8), 0, stream>>>(Wout, woutT);
    // GEMM1: qkv = xb @ wqkvT^T  (16384 x 3072, permuted cols)
    gemm_bt<1><<<dim3(24, 128), 256, 0, stream>>>(xb, wqkvT, (void*)qkv, 3072, 1024);
    // per-token attention (one wave per token, 4 waves/block, no LDS/barrier)
    attn_mfma_kernel<<<4096, 256, 0, stream>>>(qkv, ao);
    // GEMM2: out = ao @ woutT^T (fp32 out; k-dim positionally consistent)
    gemm_bt<0><<<dim3(8, 128), 256, 0, stream>>>(ao, woutT, (void*)out, 1024, 1024);
}

// Round 5
// 345.074 us; speedup vs baseline: 1.0152x; 1.0152x over previous
//
#include <hip/hip_runtime.h>
#include <hip/hip_bf16.h>
#include <cstdint>
#include <cstddef>

// Problem: B=4, T=4096, D=1024, H=16, HD=64.
// qkv = x @ Wqkv  (16384x1024 @ 1024x3072)
// per-token head-attention: scores[i,j] = q_i . k_j / 8 over heads i,j (16x16), softmax_j, out = P @ v
// final = out @ Wout (16384x1024 @ 1024x1024)
//
// Layout trick: qkv and ao are stored PERMUTED per token so the attention
// kernel's loads/stores are fully coalesced; permutations absorbed into the
// weight-transpose kernels. GEMM grids are 1D with an XCD-band swizzle:
// each XCD owns a contiguous 16-tile row band (A-band = 4 MB = one L2) and
// walks column tiles within it, so A stays L2-resident per XCD.

typedef __bf16 bf16x8 __attribute__((ext_vector_type(8)));
typedef __bf16 bf16x4 __attribute__((ext_vector_type(4)));
typedef float  f32x4  __attribute__((ext_vector_type(4)));

#define AS1 __attribute__((address_space(1)))
#define AS3 __attribute__((address_space(3)))

__device__ __forceinline__ void async_copy16(const void* g, void* l) {
    __builtin_amdgcn_global_load_lds((const AS1 void*)g, (AS3 void*)l, 16, 0, 0);
}

// position p in the permuted qkv token-row holds original column pi(p).
// q/k (g<2): col=g*1024+h*64+d -> p = g*1024 + (d&32)*16 + ((d>>3)&3)*128 + h*8 + (d&7)
// v (g==2): col=2048+j*64+d -> p = 2048 + d*16 + j   (V transposed: B-frag direct load)
__device__ __forceinline__ int invp_qkv(int col) {
    int g = col >> 10;
    if (g == 2) { int q = col & 1023; return 2048 + ((q & 63) << 4) + (q >> 6); }
    int h = (col >> 6) & 15, d = col & 63;
    return (g << 10) + ((d & 32) << 4) + (((d >> 3) & 3) << 7) + (h << 3) + (d & 7);
}

// ao position map: original k = i*64+d -> p = (i>>2)*256 + (d&15)*16 + (d>>4)*4 + (i&3)
__device__ __forceinline__ int invp_ao(int k) {
    return (((k >> 8) & 3) << 8) + ((k & 15) << 4) + (((k >> 4) & 3) << 2) + ((k >> 6) & 3);
}

// ---------------- convert fp32 -> bf16 (vectorized) ----------------
__global__ __launch_bounds__(256) void cvt_bf16_kernel(const float4* __restrict__ in,
                                                       bf16x4* __restrict__ out, int n4) {
    int i = blockIdx.x * 256 + threadIdx.x;
    if (i >= n4) return;
    float4 v = in[i];
    bf16x4 o = { (__bf16)v.x, (__bf16)v.y, (__bf16)v.z, (__bf16)v.w };
    out[i] = o;
}

// ---------------- transpose + convert Wqkv: out row order permuted ----------------
__global__ __launch_bounds__(256) void transpose_qkv_kernel(const float* __restrict__ in,
                                                            __bf16* __restrict__ out) {
    __shared__ float tile[32][33];
    const int C = 3072;
    int c0 = blockIdx.x * 32, r0 = blockIdx.y * 32;
    int tx = threadIdx.x, ty = threadIdx.y; // 32 x 8
    #pragma unroll
    for (int i = 0; i < 32; i += 8)
        tile[ty + i][tx] = in[(size_t)(r0 + ty + i) * C + c0 + tx];
    __syncthreads();
    #pragma unroll
    for (int i = 0; i < 32; i += 8) {
        int prow = invp_qkv(c0 + ty + i);
        out[(size_t)prow * 1024 + r0 + tx] = (__bf16)tile[tx][ty + i];
    }
}

// ---------------- transpose + convert Wout: k (inner) order permuted ----------------
__global__ __launch_bounds__(256) void transpose_wout_kernel(const float* __restrict__ in,
                                                             __bf16* __restrict__ out) {
    __shared__ float tile[32][33];
    const int C = 1024;
    int c0 = blockIdx.x * 32, r0 = blockIdx.y * 32;
    int tx = threadIdx.x, ty = threadIdx.y; // 32 x 8
    #pragma unroll
    for (int i = 0; i < 32; i += 8)
        tile[ty + i][tx] = in[(size_t)(r0 + ty + i) * C + c0 + tx];
    __syncthreads();
    int pk = invp_ao(r0 + tx);
    #pragma unroll
    for (int i = 0; i < 32; i += 8)
        out[(size_t)(c0 + ty + i) * 1024 + pk] = (__bf16)tile[tx][ty + i];
}

// ---------------- bf16 GEMM, C = A @ Bt^T ----------------
// A: M x K bf16 row-major, Bt: N x K bf16 row-major. 1D grid of TX*128 blocks,
// XCD-band swizzle: xcd=lin&7 owns by in [xcd*16, xcd*16+16), walks bx.
// 128x128 tile, BK=32, 4 waves in 2x2, each wave 64x64 via 4x4 mfma_16x16x32.
template<int OUT_BF16>
__global__ __launch_bounds__(256) void gemm_bt(const __bf16* __restrict__ A,
                                               const __bf16* __restrict__ Bt,
                                               void* __restrict__ Cv,
                                               int N, int K) {
    __shared__ __bf16 As[128 * 32]; // [row][k] 64B rows, k-slots xor-swizzled
    __shared__ __bf16 Bs[128 * 32];

    const int lin = blockIdx.x;
    const int xcd = lin & 7;
    const int rr  = lin >> 3;
    const int by  = xcd * 16 + (rr & 15);
    const int bx  = rr >> 4;

    const int tid  = threadIdx.x;
    const int wave = tid >> 6;
    const int lane = tid & 63;
    const int quad = lane >> 4;
    const int q16  = lane & 15;
    const int wr   = wave >> 1, wc = wave & 1;
    const int row0 = by * 128;
    const int col0 = bx * 128;

    const __bf16* Ag = A  + (size_t)row0 * K;
    const __bf16* Bg = Bt + (size_t)col0 * K;

    // per-wave staging: 2 chunks of 1KB each for A and B tiles (8KB each)
    const int o0 = (wave * 2)     * 1024 + lane * 16; // byte offset in tile
    const int o1 = (wave * 2 + 1) * 1024 + lane * 16;
    const int r0 = o0 >> 6, r1 = o1 >> 6;             // tile row (64B rows)
    const int cb0 = ((o0 >> 4) & 3) ^ ((r0 >> 1) & 3); // logical k-group (swizzle)
    const int cb1 = ((o1 >> 4) & 3) ^ ((r1 >> 1) & 3);
    char* ldsA0 = (char*)As + (wave * 2)     * 1024;
    char* ldsA1 = (char*)As + (wave * 2 + 1) * 1024;
    char* ldsB0 = (char*)Bs + (wave * 2)     * 1024;
    char* ldsB1 = (char*)Bs + (wave * 2 + 1) * 1024;

    f32x4 acc[4][4] = {};

    for (int k0 = 0; k0 < K; k0 += 32) {
        async_copy16(Ag + (size_t)r0 * K + (k0 + cb0 * 8), ldsA0);
        async_copy16(Ag + (size_t)r1 * K + (k0 + cb1 * 8), ldsA1);
        async_copy16(Bg + (size_t)r0 * K + (k0 + cb0 * 8), ldsB0);
        async_copy16(Bg + (size_t)r1 * K + (k0 + cb1 * 8), ldsB1);
        __syncthreads(); // drains vmcnt(0): staged data visible

        bf16x8 af[4], bfr[4];
        #pragma unroll
        for (int mi = 0; mi < 4; ++mi) {
            int row = wr * 64 + mi * 16 + q16;
            int sl  = quad ^ ((row >> 1) & 3);
            af[mi] = *(const bf16x8*)((const char*)As + row * 64 + sl * 16);
        }
        #pragma unroll
        for (int ni = 0; ni < 4; ++ni) {
            int row = wc * 64 + ni * 16 + q16;
            int sl  = quad ^ ((row >> 1) & 3);
            bfr[ni] = *(const bf16x8*)((const char*)Bs + row * 64 + sl * 16);
        }
        #pragma unroll
        for (int mi = 0; mi < 4; ++mi)
            #pragma unroll
            for (int ni = 0; ni < 4; ++ni)
                acc[mi][ni] = __builtin_amdgcn_mfma_f32_16x16x32_bf16(af[mi], bfr[ni], acc[mi][ni], 0, 0, 0);
        __syncthreads(); // all reads done before next stage overwrites
    }

    // epilogue: D row = quad*4 + reg, col = q16 (per 16x16 tile)
    #pragma unroll
    for (int mi = 0; mi < 4; ++mi) {
        #pragma unroll
        for (int ni = 0; ni < 4; ++ni) {
            int col = col0 + wc * 64 + ni * 16 + q16;
            #pragma unroll
            for (int r = 0; r < 4; ++r) {
                int row = row0 + wr * 64 + mi * 16 + quad * 4 + r;
                if (OUT_BF16)
                    ((__bf16*)Cv)[(size_t)row * N + col] = (__bf16)acc[mi][ni][r];
                else
                    ((float*)Cv)[(size_t)row * N + col] = acc[mi][ni][r];
            }
        }
    }
}

// ---------------- per-token head attention, MFMA, one wave per token ----------------
// qkv token-row is in permuted layout (see invp_qkv): all loads coalesced,
// V pre-transposed -> direct B-frag loads. No LDS, no barriers.
__global__ __launch_bounds__(256) void attn_mfma_kernel(const __bf16* __restrict__ qkv,
                                                        __bf16* __restrict__ ao) {
    const int tok  = blockIdx.x * 4 + (threadIdx.x >> 6);
    const int lane = threadIdx.x & 63;
    const int quad = lane >> 4;
    const int q16  = lane & 15;

    const __bf16* base = qkv + (size_t)tok * 3072;

    // coalesced A-frag loads (layout puts lane's fragment at lane*8)
    const bf16x8 qf0 = *(const bf16x8*)(base + lane * 8);
    const bf16x8 qf1 = *(const bf16x8*)(base + 512 + lane * 8);
    const bf16x8 kf0 = *(const bf16x8*)(base + 1024 + lane * 8);
    const bf16x8 kf1 = *(const bf16x8*)(base + 1536 + lane * 8);

    // S^T[j][i] = sum_d k[j][d] q[i][d]
    f32x4 st = {0.f, 0.f, 0.f, 0.f};
    st = __builtin_amdgcn_mfma_f32_16x16x32_bf16(kf0, qf0, st, 0, 0, 0);
    st = __builtin_amdgcn_mfma_f32_16x16x32_bf16(kf1, qf1, st, 0, 0, 0);

    // softmax over j (= 4 regs x 4 quads) for fixed i = q16
    float s0 = st[0] * 0.125f, s1 = st[1] * 0.125f, s2 = st[2] * 0.125f, s3 = st[3] * 0.125f;
    float m = fmaxf(fmaxf(s0, s1), fmaxf(s2, s3));
    m = fmaxf(m, __shfl_xor(m, 16));
    m = fmaxf(m, __shfl_xor(m, 32));
    float e0 = __expf(s0 - m), e1 = __expf(s1 - m), e2 = __expf(s2 - m), e3 = __expf(s3 - m);
    float sum = e0 + e1 + e2 + e3;
    sum += __shfl_xor(sum, 16);
    sum += __shfl_xor(sum, 32);
    const float inv = 1.f / sum;

    // pack P^T lane values (j = quad*4 + r, i = q16) into 2 dwords of bf16
    union { __bf16 h[2]; int i; } u01, u23;
    u01.h[0] = (__bf16)(e0 * inv); u01.h[1] = (__bf16)(e1 * inv);
    u23.h[0] = (__bf16)(e2 * inv); u23.h[1] = (__bf16)(e3 * inv);

    // A-frag of P for 16x16x32 (K padded to 32): lane needs P[q16][quad*8+idx]
    const int src0 = quad * 32 + q16;
    const int src1 = src0 + 16;
    union { int i[4]; bf16x8 v; } af;
    af.i[0] = __shfl(u01.i, src0);
    af.i[1] = __shfl(u23.i, src0);
    af.i[2] = __shfl(u01.i, src1);
    af.i[3] = __shfl(u23.i, src1);
    if (quad >= 2) { af.i[0] = 0; af.i[1] = 0; af.i[2] = 0; af.i[3] = 0; }

    // PV: V region is pre-transposed [d][j]; B-frag chunk c is a direct load.
    const __bf16* vb = base + 2048;
    f32x4 accs[4];
    #pragma unroll
    for (int c = 0; c < 4; ++c) {
        bf16x8 bfv = {};
        if (quad < 2)
            bfv = *(const bf16x8*)(vb + (c * 16 + q16) * 16 + quad * 8);
        f32x4 z = {0.f, 0.f, 0.f, 0.f};
        accs[c] = __builtin_amdgcn_mfma_f32_16x16x32_bf16(af.v, bfv, z, 0, 0, 0);
    }

    // store: lane's 16 values contiguously at p = lane*16 (invp_ao layout)
    union { __bf16 h[16]; bf16x8 v[2]; } o;
    #pragma unroll
    for (int c = 0; c < 4; ++c)
        #pragma unroll
        for (int r = 0; r < 4; ++r)
            o.h[c * 4 + r] = (__bf16)accs[c][r];
    __bf16* outp = ao + (size_t)tok * 1024 + lane * 16;
    *(bf16x8*)outp = o.v[0];
    *(bf16x8*)(outp + 8) = o.v[1];
}

// ---------------- launch ----------------
extern "C" void kernel_launch(void* const* d_in, const int* in_sizes, int n_in,
                              void* d_out, int out_size, void* d_ws, size_t ws_size,
                              hipStream_t stream) {
    const float* x    = (const float*)d_in[0]; // 16384 x 1024
    const float* Wqkv = (const float*)d_in[1]; // 1024 x 3072
    const float* Wout = (const float*)d_in[2]; // 1024 x 1024
    float* out = (float*)d_out;                // 16384 x 1024

    char* ws = (char*)d_ws;
    __bf16* xb    = (__bf16*)(ws);                                   // 32 MiB
    __bf16* wqkvT = (__bf16*)(ws + 33554432);                        // 6 MiB  (3072 x 1024, row-permuted)
    __bf16* woutT = (__bf16*)(ws + 33554432 + 6291456);              // 2 MiB  (1024 x 1024, k-permuted)
    __bf16* qkv   = (__bf16*)(ws + 33554432 + 6291456 + 2097152);    // 96 MiB (16384 x 3072, permuted)
    __bf16* ao    = (__bf16*)(ws + 33554432 + 6291456 + 2097152 + 100663296); // 32 MiB (permuted)

    // convert x (16M elems, 4/thread)
    cvt_bf16_kernel<<<16384, 256, 0, stream>>>((const float4*)x, (bf16x4*)xb, 4194304);
    // transpose+convert weights (with absorbed layout permutations)
    transpose_qkv_kernel<<<dim3(96, 32), dim3(32, 8), 0, stream>>>(Wqkv, wqkvT);
    transpose_wout_kernel<<<dim3(32, 32), dim3(32, 8), 0, stream>>>(Wout, woutT);
    // GEMM1: qkv = xb @ wqkvT^T  (16384 x 3072), 1D grid 24*128, XCD-band swizzle
    gemm_bt<1><<<24 * 128, 256, 0, stream>>>(xb, wqkvT, (void*)qkv, 3072, 1024);
    // per-token attention (one wave per token, 4 waves/block, no LDS/barrier)
    attn_mfma_kernel<<<4096, 256, 0, stream>>>(qkv, ao);
    // GEMM2: out = ao @ woutT^T (fp32 out), 1D grid 8*128, XCD-band swizzle
    gemm_bt<0><<<8 * 128, 256, 0, stream>>>(ao, woutT, (void*)out, 1024, 1024);
}

// Round 7
// 318.233 us; speedup vs baseline: 1.1008x; 1.0843x over previous
//
#include <hip/hip_runtime.h>
#include <hip/hip_bf16.h>
#include <cstdint>
#include <cstddef>

// Problem: B=4, T=4096, D=1024, H=16, HD=64.
// qkv = x @ Wqkv  (16384x1024 @ 1024x3072)
// per-token head-attention: scores[i,j] = q_i . k_j / 8 over heads i,j (16x16), softmax_j, out = P @ v
// final = out @ Wout (16384x1024 @ 1024x1024)
//
// qkv/ao stored permuted per token (absorbed into weight transposes) so attn
// is fully coalesced. GEMMs: 1D grid with XCD-band swizzle (A-band L2-resident
// per XCD; FETCH 143->90 MB measured). This round: BK=64 K-loop — 32 MFMA +
// 16 ds_read_b128 + 8 batched global_load_lds per barrier-pair (halves barrier
// drains vs BK=32).

typedef __bf16 bf16x8 __attribute__((ext_vector_type(8)));
typedef __bf16 bf16x4 __attribute__((ext_vector_type(4)));
typedef float  f32x4  __attribute__((ext_vector_type(4)));

#define AS1 __attribute__((address_space(1)))
#define AS3 __attribute__((address_space(3)))

__device__ __forceinline__ void async_copy16(const void* g, void* l) {
    __builtin_amdgcn_global_load_lds((const AS1 void*)g, (AS3 void*)l, 16, 0, 0);
}

// position p in the permuted qkv token-row holds original column pi(p).
// q/k (g<2): col=g*1024+h*64+d -> p = g*1024 + (d&32)*16 + ((d>>3)&3)*128 + h*8 + (d&7)
// v (g==2): col=2048+j*64+d -> p = 2048 + d*16 + j   (V transposed: B-frag direct load)
__device__ __forceinline__ int invp_qkv(int col) {
    int g = col >> 10;
    if (g == 2) { int q = col & 1023; return 2048 + ((q & 63) << 4) + (q >> 6); }
    int h = (col >> 6) & 15, d = col & 63;
    return (g << 10) + ((d & 32) << 4) + (((d >> 3) & 3) << 7) + (h << 3) + (d & 7);
}

// ao position map: original k = i*64+d -> p = (i>>2)*256 + (d&15)*16 + (d>>4)*4 + (i&3)
__device__ __forceinline__ int invp_ao(int k) {
    return (((k >> 8) & 3) << 8) + ((k & 15) << 4) + (((k >> 4) & 3) << 2) + ((k >> 6) & 3);
}

// ---------------- convert fp32 -> bf16 (vectorized) ----------------
__global__ __launch_bounds__(256) void cvt_bf16_kernel(const float4* __restrict__ in,
                                                       bf16x4* __restrict__ out, int n4) {
    int i = blockIdx.x * 256 + threadIdx.x;
    if (i >= n4) return;
    float4 v = in[i];
    bf16x4 o = { (__bf16)v.x, (__bf16)v.y, (__bf16)v.z, (__bf16)v.w };
    out[i] = o;
}

// ---------------- transpose + convert Wqkv: out row order permuted ----------------
__global__ __launch_bounds__(256) void transpose_qkv_kernel(const float* __restrict__ in,
                                                            __bf16* __restrict__ out) {
    __shared__ float tile[32][33];
    const int C = 3072;
    int c0 = blockIdx.x * 32, r0 = blockIdx.y * 32;
    int tx = threadIdx.x, ty = threadIdx.y; // 32 x 8
    #pragma unroll
    for (int i = 0; i < 32; i += 8)
        tile[ty + i][tx] = in[(size_t)(r0 + ty + i) * C + c0 + tx];
    __syncthreads();
    #pragma unroll
    for (int i = 0; i < 32; i += 8) {
        int prow = invp_qkv(c0 + ty + i);
        out[(size_t)prow * 1024 + r0 + tx] = (__bf16)tile[tx][ty + i];
    }
}

// ---------------- transpose + convert Wout: k (inner) order permuted ----------------
__global__ __launch_bounds__(256) void transpose_wout_kernel(const float* __restrict__ in,
                                                             __bf16* __restrict__ out) {
    __shared__ float tile[32][33];
    const int C = 1024;
    int c0 = blockIdx.x * 32, r0 = blockIdx.y * 32;
    int tx = threadIdx.x, ty = threadIdx.y; // 32 x 8
    #pragma unroll
    for (int i = 0; i < 32; i += 8)
        tile[ty + i][tx] = in[(size_t)(r0 + ty + i) * C + c0 + tx];
    __syncthreads();
    int pk = invp_ao(r0 + tx);
    #pragma unroll
    for (int i = 0; i < 32; i += 8)
        out[(size_t)(c0 + ty + i) * 1024 + pk] = (__bf16)tile[tx][ty + i];
}

// ---------------- bf16 GEMM, C = A @ Bt^T, BK=64 ----------------
// A: M x K bf16 row-major, Bt: N x K bf16 row-major. 1D grid of TX*128 blocks,
// XCD-band swizzle: xcd=lin&7 owns by in [xcd*16, xcd*16+16), walks bx.
// 128x128 tile, BK=64 (32 KB LDS), 4 waves 2x2, each wave 64x64 via 4x4 mfma.
// LDS rows are 128 B (64 bf16), 8 16-B slots, swizzle phys = slot ^ (row&7):
// staging lane l -> row +l>>3, kslot (l&7)^(l>>3); frag read phys=(s*4+quad)^(q16&7).
// Per-instr bank load is exactly 8 words/bank -> conflict-free (b128 minimum).
template<int OUT_BF16>
__global__ __launch_bounds__(256) void gemm_bt(const __bf16* __restrict__ A,
                                               const __bf16* __restrict__ Bt,
                                               void* __restrict__ Cv,
                                               int N, int K) {
    __shared__ __bf16 As[128 * 64]; // 16 KB
    __shared__ __bf16 Bs[128 * 64]; // 16 KB

    const int lin = blockIdx.x;
    const int xcd = lin & 7;
    const int rr  = lin >> 3;
    const int by  = xcd * 16 + (rr & 15);
    const int bx  = rr >> 4;

    const int tid  = threadIdx.x;
    const int wave = tid >> 6;
    const int lane = tid & 63;
    const int quad = lane >> 4;
    const int q16  = lane & 15;
    const int wr   = wave >> 1, wc = wave & 1;
    const int row0 = by * 128;
    const int col0 = bx * 128;

    const __bf16* Ag = A  + (size_t)row0 * K;
    const __bf16* Bg = Bt + (size_t)col0 * K;

    // staging constants (per thread): chunk g covers rows g*32..+31
    const int l8 = lane >> 3;          // 0..7
    const int l7 = lane & 7;           // 0..7
    const int srow = wave * 8 + l8;    // row within chunk: + g*32
    const int skoff = (l7 ^ l8) << 3;  // element k-offset of this lane's 16B
    char* dstA = (char*)As + wave * 1024;
    char* dstB = (char*)Bs + wave * 1024;

    // frag-read phys slot xor
    const int rx = q16 & 7;

    f32x4 acc[4][4] = {};

    for (int k0 = 0; k0 < K; k0 += 64) {
        #pragma unroll
        for (int g = 0; g < 4; ++g) {
            const size_t roff = (size_t)(g * 32 + srow) * K + (k0 + skoff);
            async_copy16(Ag + roff, dstA + g * 4096);
            async_copy16(Bg + roff, dstB + g * 4096);
        }
        __syncthreads(); // drains vmcnt(0): staged data visible

        #pragma unroll
        for (int s = 0; s < 2; ++s) {
            const int ps = (s * 4 + quad);
            bf16x8 af[4], bfr[4];
            #pragma unroll
            for (int mi = 0; mi < 4; ++mi) {
                int row = wr * 64 + mi * 16 + q16;
                af[mi] = *(const bf16x8*)((const char*)As + row * 128 + ((ps ^ rx) << 4));
            }
            #pragma unroll
            for (int ni = 0; ni < 4; ++ni) {
                int row = wc * 64 + ni * 16 + q16;
                bfr[ni] = *(const bf16x8*)((const char*)Bs + row * 128 + ((ps ^ rx) << 4));
            }
            #pragma unroll
            for (int mi = 0; mi < 4; ++mi)
                #pragma unroll
                for (int ni = 0; ni < 4; ++ni)
                    acc[mi][ni] = __builtin_amdgcn_mfma_f32_16x16x32_bf16(af[mi], bfr[ni], acc[mi][ni], 0, 0, 0);
        }
        __syncthreads(); // all reads done before next stage overwrites
    }

    // epilogue: D row = quad*4 + reg, col = q16 (per 16x16 tile)
    #pragma unroll
    for (int mi = 0; mi < 4; ++mi) {
        #pragma unroll
        for (int ni = 0; ni < 4; ++ni) {
            int col = col0 + wc * 64 + ni * 16 + q16;
            #pragma unroll
            for (int r = 0; r < 4; ++r) {
                int row = row0 + wr * 64 + mi * 16 + quad * 4 + r;
                if (OUT_BF16)
                    ((__bf16*)Cv)[(size_t)row * N + col] = (__bf16)acc[mi][ni][r];
                else
                    ((float*)Cv)[(size_t)row * N + col] = acc[mi][ni][r];
            }
        }
    }
}

// ---------------- per-token head attention, MFMA, one wave per token ----------------
// qkv token-row is in permuted layout (see invp_qkv): all loads coalesced,
// V pre-transposed -> direct B-frag loads. No LDS, no barriers.
__global__ __launch_bounds__(256) void attn_mfma_kernel(const __bf16* __restrict__ qkv,
                                                        __bf16* __restrict__ ao) {
    const int tok  = blockIdx.x * 4 + (threadIdx.x >> 6);
    const int lane = threadIdx.x & 63;
    const int quad = lane >> 4;
    const int q16  = lane & 15;

    const __bf16* base = qkv + (size_t)tok * 3072;

    // coalesced A-frag loads (layout puts lane's fragment at lane*8)
    const bf16x8 qf0 = *(const bf16x8*)(base + lane * 8);
    const bf16x8 qf1 = *(const bf16x8*)(base + 512 + lane * 8);
    const bf16x8 kf0 = *(const bf16x8*)(base + 1024 + lane * 8);
    const bf16x8 kf1 = *(const bf16x8*)(base + 1536 + lane * 8);

    // S^T[j][i] = sum_d k[j][d] q[i][d]
    f32x4 st = {0.f, 0.f, 0.f, 0.f};
    st = __builtin_amdgcn_mfma_f32_16x16x32_bf16(kf0, qf0, st, 0, 0, 0);
    st = __builtin_amdgcn_mfma_f32_16x16x32_bf16(kf1, qf1, st, 0, 0, 0);

    // softmax over j (= 4 regs x 4 quads) for fixed i = q16
    float s0 = st[0] * 0.125f, s1 = st[1] * 0.125f, s2 = st[2] * 0.125f, s3 = st[3] * 0.125f;
    float m = fmaxf(fmaxf(s0, s1), fmaxf(s2, s3));
    m = fmaxf(m, __shfl_xor(m, 16));
    m = fmaxf(m, __shfl_xor(m, 32));
    float e0 = __expf(s0 - m), e1 = __expf(s1 - m), e2 = __expf(s2 - m), e3 = __expf(s3 - m);
    float sum = e0 + e1 + e2 + e3;
    sum += __shfl_xor(sum, 16);
    sum += __shfl_xor(sum, 32);
    const float inv = 1.f / sum;

    // pack P^T lane values (j = quad*4 + r, i = q16) into 2 dwords of bf16
    union { __bf16 h[2]; int i; } u01, u23;
    u01.h[0] = (__bf16)(e0 * inv); u01.h[1] = (__bf16)(e1 * inv);
    u23.h[0] = (__bf16)(e2 * inv); u23.h[1] = (__bf16)(e3 * inv);

    // A-frag of P for 16x16x32 (K padded to 32): lane needs P[q16][quad*8+idx]
    const int src0 = quad * 32 + q16;
    const int src1 = src0 + 16;
    union { int i[4]; bf16x8 v; } af;
    af.i[0] = __shfl(u01.i, src0);
    af.i[1] = __shfl(u23.i, src0);
    af.i[2] = __shfl(u01.i, src1);
    af.i[3] = __shfl(u23.i, src1);
    if (quad >= 2) { af.i[0] = 0; af.i[1] = 0; af.i[2] = 0; af.i[3] = 0; }

    // PV: V region is pre-transposed [d][j]; B-frag chunk c is a direct load.
    const __bf16* vb = base + 2048;
    f32x4 accs[4];
    #pragma unroll
    for (int c = 0; c < 4; ++c) {
        bf16x8 bfv = {};
        if (quad < 2)
            bfv = *(const bf16x8*)(vb + (c * 16 + q16) * 16 + quad * 8);
        f32x4 z = {0.f, 0.f, 0.f, 0.f};
        accs[c] = __builtin_amdgcn_mfma_f32_16x16x32_bf16(af.v, bfv, z, 0, 0, 0);
    }

    // store: lane's 16 values contiguously at p = lane*16 (invp_ao layout)
    union { __bf16 h[16]; bf16x8 v[2]; } o;
    #pragma unroll
    for (int c = 0; c < 4; ++c)
        #pragma unroll
        for (int r = 0; r < 4; ++r)
            o.h[c * 4 + r] = (__bf16)accs[c][r];
    __bf16* outp = ao + (size_t)tok * 1024 + lane * 16;
    *(bf16x8*)outp = o.v[0];
    *(bf16x8*)(outp + 8) = o.v[1];
}

// ---------------- launch ----------------
extern "C" void kernel_launch(void* const* d_in, const int* in_sizes, int n_in,
                              void* d_out, int out_size, void* d_ws, size_t ws_size,
                              hipStream_t stream) {
    const float* x    = (const float*)d_in[0]; // 16384 x 1024
    const float* Wqkv = (const float*)d_in[1]; // 1024 x 3072
    const float* Wout = (const float*)d_in[2]; // 1024 x 1024
    float* out = (float*)d_out;                // 16384 x 1024

    char* ws = (char*)d_ws;
    __bf16* xb    = (__bf16*)(ws);                                   // 32 MiB
    __bf16* wqkvT = (__bf16*)(ws + 33554432);                        // 6 MiB  (3072 x 1024, row-permuted)
    __bf16* woutT = (__bf16*)(ws + 33554432 + 6291456);              // 2 MiB  (1024 x 1024, k-permuted)
    __bf16* qkv   = (__bf16*)(ws + 33554432 + 6291456 + 2097152);    // 96 MiB (16384 x 3072, permuted)
    __bf16* ao    = (__bf16*)(ws + 33554432 + 6291456 + 2097152 + 100663296); // 32 MiB (permuted)

    // convert x (16M elems, 4/thread)
    cvt_bf16_kernel<<<16384, 256, 0, stream>>>((const float4*)x, (bf16x4*)xb, 4194304);
    // transpose+convert weights (with absorbed layout permutations)
    transpose_qkv_kernel<<<dim3(96, 32), dim3(32, 8), 0, stream>>>(Wqkv, wqkvT);
    transpose_wout_kernel<<<dim3(32, 32), dim3(32, 8), 0, stream>>>(Wout, woutT);
    // GEMM1: qkv = xb @ wqkvT^T  (16384 x 3072), 1D grid 24*128, XCD-band swizzle
    gemm_bt<1><<<24 * 128, 256, 0, stream>>>(xb, wqkvT, (void*)qkv, 3072, 1024);
    // per-token attention (one wave per token, 4 waves/block, no LDS/barrier)
    attn_mfma_kernel<<<4096, 256, 0, stream>>>(qkv, ao);
    // GEMM2: out = ao @ woutT^T (fp32 out), 1D grid 8*128, XCD-band swizzle
    gemm_bt<0><<<8 * 128, 256, 0, stream>>>(ao, woutT, (void*)out, 1024, 1024);
}